// Round 5
// baseline (161.614 us; speedup 1.0000x reference)
//
#include <hip/hip_runtime.h>
#include <hip/hip_bf16.h>
#include <math.h>

typedef unsigned short u16;
typedef __bf16 bf16x8 __attribute__((ext_vector_type(8)));
typedef float f32x4 __attribute__((ext_vector_type(4)));
typedef unsigned short u16x4 __attribute__((ext_vector_type(4)));
typedef unsigned short u16x8 __attribute__((ext_vector_type(8)));

#define BB 4
#define LL 4096
#define MTOK (BB*LL)
#define HID 1024
#define NKV 2048
#define KDIM 1024
#define VOCABN 32000
#define EPSF 1e-6f

__device__ __forceinline__ float bf2f(u16 x) {
  unsigned u = ((unsigned)x) << 16;
  return __builtin_bit_cast(float, u);
}
__device__ __forceinline__ u16 f2bf(float f) {
  unsigned u = __builtin_bit_cast(unsigned, f);
  u += 0x7FFFu + ((u >> 16) & 1u);
  return (u16)(u >> 16);
}

// ---------------- kernel 1: convert w_k || w_v -> bf16 W[2048][1024] ----------------
__global__ __launch_bounds__(256) void k_convert_w(const float* __restrict__ wk,
                                                   const float* __restrict__ wv,
                                                   u16* __restrict__ W) {
  int i = blockIdx.x * 256 + threadIdx.x;
  const int n4 = (NKV * KDIM) / 4;
  if (i >= n4) return;
  const int half = n4 / 2;
  const f32x4* src = (i < half) ? (const f32x4*)wk : (const f32x4*)wv;
  int j = (i < half) ? i : i - half;
  f32x4 v = src[j];
  u16x4 o = { f2bf(v[0]), f2bf(v[1]), f2bf(v[2]), f2bf(v[3]) };
  *(u16x4*)&W[(size_t)i * 4] = o;
}

// ---------------- kernel 2: hash + gather, 16 tokens/block ----------------
__global__ __launch_bounds__(256) void k_gather(
    const int* __restrict__ tok, const int* __restrict__ proj,
    const int* __restrict__ m2, const int* __restrict__ m3,
    const int* __restrict__ tsz, const float* __restrict__ tables,
    int max_s, u16* __restrict__ mem) {
  __shared__ int sidx[16][16];    // [token][table]
  const int m0 = blockIdx.x * 16;
  const int tid = threadIdx.x;
  const int tt = tid >> 4;        // token 0..15
  const int t = tid & 15;         // table 0..15
  const int m = m0 + tt;
  const int l = m & (LL - 1);

  long long c0, c1 = 0, c2 = 0;
  {
    int tk = tok[m];
    tk = tk < 0 ? 0 : (tk > VOCABN - 1 ? VOCABN - 1 : tk);
    c0 = proj[tk];
  }
  if (l >= 1) {
    int tk = tok[m - 1];
    tk = tk < 0 ? 0 : (tk > VOCABN - 1 ? VOCABN - 1 : tk);
    c1 = proj[tk];
  }
  if (l >= 2) {
    int tk = tok[m - 2];
    tk = tk < 0 ? 0 : (tk > VOCABN - 1 ? VOCABN - 1 : tk);
    c2 = proj[tk];
  }
  int order = t >> 3, h = t & 7;
  long long mix;
  if (order == 0) {
    mix = (c1 * (long long)m2[h * 2 + 0]) ^ (c0 * (long long)m2[h * 2 + 1]);
  } else {
    mix = (c2 * (long long)m3[h * 3 + 0]) ^ (c1 * (long long)m3[h * 3 + 1]) ^
          (c0 * (long long)m3[h * 3 + 2]);
  }
  unsigned long long um = (unsigned long long)(mix < 0 ? -mix : mix);
  unsigned long long usz = (unsigned long long)tsz[t];
  unsigned long long qq = (unsigned long long)((double)um / (double)usz);
  long long r = (long long)(um - qq * usz);
  if (r < 0) r += (long long)usz;
  else if (r >= (long long)usz) r -= (long long)usz;
  sidx[tt][t] = (int)r;
  __syncthreads();

  // gather: thread = (token tt, quad q); 16 independent 16B loads in flight
  const int q = t;
#pragma unroll
  for (int it = 0; it < 16; ++it) {
    int idx = sidx[tt][it];
    const f32x4* src = (const f32x4*)(tables + ((size_t)it * (size_t)max_s + (size_t)idx) * 64);
    f32x4 e = src[q];
    u16x4 o = { f2bf(e[0]), f2bf(e[1]), f2bf(e[2]), f2bf(e[3]) };
    *(u16x4*)&mem[(size_t)m * HID + it * 64 + q * 4] = o;
  }
}

// ---------------- kernel 3: 256x256 GEMM, BK=32, 4-buffer 3-deep, 2-phase tiles ----------------
#define GBK2 32
#define BUF2 32768

__device__ __forceinline__ void gload16(const void* g, void* l) {
  __builtin_amdgcn_global_load_lds((__attribute__((address_space(1))) void*)(g),
                                   (__attribute__((address_space(3))) void*)(l), 16, 0, 0);
}
__device__ __forceinline__ int swz32(int x) { return x ^ (((x >> 6) & 3) << 4); }

__global__ __launch_bounds__(512, 2) void k_gemm(const u16* __restrict__ A,
                                                 const u16* __restrict__ Bw,
                                                 u16* __restrict__ C) {
  __shared__ __align__(16) char lds[131072];
  const int d = blockIdx.x;
  const int wg = (d & 7) * 64 + (d >> 3);     // XCD-bijective (512 % 8 == 0)
  const int bm = wg >> 3, bn = wg & 7;
  const int tid = threadIdx.x;
  const int w = tid >> 6, lane = tid & 63;
  const int wm = w >> 2, wn = w & 3;
  const int lm = lane & 15, kg = lane >> 4;

  const int ca0 = w * 2, ca1 = w * 2 + 1;
  const int row0 = ca0 * 16 + (lane >> 2);
  const int row1 = ca1 * 16 + (lane >> 2);
  const int off0 = row0 * KDIM + (((lane & 3) ^ (row0 & 3)) << 3);
  const int off1 = row1 * KDIM + (((lane & 3) ^ (row1 & 3)) << 3);
  const int dstA0 = ca0 * 1024 + lane * 16;
  const int dstA1 = ca1 * 1024 + lane * 16;
  const u16* Ap = A + (size_t)bm * 256 * KDIM;
  const u16* Bp = Bw + (size_t)bn * 256 * KDIM;

  int aro[8], bro[4];
#pragma unroll
  for (int mi = 0; mi < 8; ++mi)
    aro[mi] = swz32((wm * 128 + mi * 16 + lm) * 64 + kg * 16);
#pragma unroll
  for (int ni = 0; ni < 4; ++ni)
    bro[ni] = 16384 + swz32((wn * 64 + ni * 16 + lm) * 64 + kg * 16);

  f32x4 acc[8][4];
#pragma unroll
  for (int i = 0; i < 8; ++i)
#pragma unroll
    for (int j = 0; j < 4; ++j) acc[i][j] = (f32x4){0.f, 0.f, 0.f, 0.f};

#define STGA(kt, bb)                                                       \
  {                                                                        \
    char* bbase = lds + (bb) * BUF2;                                       \
    gload16(Ap + off0 + (kt) * GBK2, bbase + dstA0);                       \
    gload16(Ap + off1 + (kt) * GBK2, bbase + dstA1);                       \
  }
#define STGB(kt, bb)                                                       \
  {                                                                        \
    char* bbase = lds + (bb) * BUF2;                                       \
    gload16(Bp + off0 + (kt) * GBK2, bbase + 16384 + dstA0);               \
    gload16(Bp + off1 + (kt) * GBK2, bbase + 16384 + dstA1);               \
  }

#define TILE(t, bb, VMS, DOSTG)                                            \
  {                                                                        \
    asm volatile("s_waitcnt vmcnt(" VMS ")" ::: "memory");                 \
    __builtin_amdgcn_s_barrier();                                          \
    const char* buf = lds + (bb) * BUF2;                                   \
    bf16x8 af0[4], bfr[4], af1[4];                                         \
    _Pragma("unroll")                                                      \
    for (int mi = 0; mi < 4; ++mi) af0[mi] = *(const bf16x8*)(buf + aro[mi]); \
    _Pragma("unroll")                                                      \
    for (int ni = 0; ni < 4; ++ni) bfr[ni] = *(const bf16x8*)(buf + bro[ni]); \
    if (DOSTG) STGA((t) + 3, ((bb) + 3) & 3);                              \
    asm volatile("s_waitcnt lgkmcnt(0)" ::: "memory");                     \
    __builtin_amdgcn_sched_barrier(0);                                     \
    __builtin_amdgcn_s_setprio(1);                                         \
    _Pragma("unroll")                                                      \
    for (int mi = 0; mi < 4; ++mi)                                         \
      _Pragma("unroll")                                                    \
      for (int ni = 0; ni < 4; ++ni)                                       \
        acc[mi][ni] = __builtin_amdgcn_mfma_f32_16x16x32_bf16(af0[mi], bfr[ni], acc[mi][ni], 0, 0, 0); \
    __builtin_amdgcn_s_setprio(0);                                         \
    __builtin_amdgcn_s_barrier();                                          \
    _Pragma("unroll")                                                      \
    for (int mi = 0; mi < 4; ++mi) af1[mi] = *(const bf16x8*)(buf + aro[4 + mi]); \
    if (DOSTG) STGB((t) + 3, ((bb) + 3) & 3);                              \
    asm volatile("s_waitcnt lgkmcnt(0)" ::: "memory");                     \
    __builtin_amdgcn_sched_barrier(0);                                     \
    __builtin_amdgcn_s_setprio(1);                                         \
    _Pragma("unroll")                                                      \
    for (int mi = 0; mi < 4; ++mi)                                         \
      _Pragma("unroll")                                                    \
      for (int ni = 0; ni < 4; ++ni)                                       \
        acc[4 + mi][ni] = __builtin_amdgcn_mfma_f32_16x16x32_bf16(af1[mi], bfr[ni], acc[4 + mi][ni], 0, 0, 0); \
    __builtin_amdgcn_s_setprio(0);                                         \
  }

  STGA(0, 0); STGB(0, 0);
  STGA(1, 1); STGB(1, 1);
  STGA(2, 2); STGB(2, 2);
#pragma unroll 1
  for (int t4 = 0; t4 < 7; ++t4) {
    const int t = t4 * 4;
    TILE(t + 0, 0, "8", 1);
    TILE(t + 1, 1, "8", 1);
    TILE(t + 2, 2, "8", 1);
    TILE(t + 3, 3, "8", 1);
  }
  TILE(28, 0, "8", 1);   // stages tile 31
  TILE(29, 1, "8", 0);
  TILE(30, 2, "4", 0);
  TILE(31, 3, "0", 0);
#undef STGA
#undef STGB
#undef TILE

  // ---- epilogue: LDS transpose -> coalesced 16B stores ----
  __syncthreads();
  u16* tile = (u16*)lds;
#pragma unroll
  for (int mi = 0; mi < 8; ++mi)
#pragma unroll
    for (int ni = 0; ni < 4; ++ni)
#pragma unroll
      for (int jj = 0; jj < 4; ++jj) {
        int r = wm * 128 + mi * 16 + kg * 4 + jj;
        int ccol = wn * 64 + ni * 16 + lm;
        tile[r * 256 + ccol] = f2bf(acc[mi][ni][jj]);
      }
  __syncthreads();
#pragma unroll
  for (int it = 0; it < 8; ++it) {
    int r = it * 32 + (tid >> 4);
    int cb = (tid & 15) * 32;
    *(f32x4*)((char*)C + ((size_t)(bm * 256 + r) * NKV + bn * 256) * 2 + cb) =
        *(const f32x4*)((char*)tile + r * 512 + cb);
    *(f32x4*)((char*)C + ((size_t)(bm * 256 + r) * NKV + bn * 256) * 2 + cb + 16) =
        *(const f32x4*)((char*)tile + r * 512 + cb + 16);
  }
}

// ---------------- kernel 4: fused gate+conv, wave-per-row, 16-slot ring ----------------
#define CR 32

__global__ __launch_bounds__(256, 3) void k_gateconv(
    const float* __restrict__ hidden, const u16* __restrict__ KV,
    const float* __restrict__ qw, const float* __restrict__ kw,
    const float* __restrict__ cw, const float* __restrict__ convw,
    const float* __restrict__ convb, float* __restrict__ out) {
  __shared__ u16 ring[16][1024];   // 32KB bf16 h-history, slot = row & 15
  __shared__ f32x4 cwt[1024];      // 16KB conv weights, bank-swizzled
  const int blk = blockIdx.x;
  const int b = blk >> 7;
  const int l0 = (blk & 127) * CR;
  const int w = threadIdx.x >> 6, ln = threadIdx.x & 63;

  // stage conv weights to LDS (swizzled: phys = i ^ (i>>3 & 7))
  {
    const f32x4* cw4 = (const f32x4*)convw;
#pragma unroll
    for (int j = 0; j < 4; ++j) {
      int i = threadIdx.x * 4 + j;
      cwt[i ^ ((i >> 3) & 7)] = cw4[i];
    }
  }

  // persistent per-lane weights
  float qk[16], cwv[16];
  f32x4 cbv[4];
#pragma unroll
  for (int seg = 0; seg < 2; ++seg) {
    int c0 = seg * 512 + ln * 8;
    f32x4 qa = *(const f32x4*)&qw[c0], qb = *(const f32x4*)&qw[c0 + 4];
    f32x4 ka = *(const f32x4*)&kw[c0], kb = *(const f32x4*)&kw[c0 + 4];
    f32x4 ca = *(const f32x4*)&cw[c0], cbx = *(const f32x4*)&cw[c0 + 4];
#pragma unroll
    for (int i = 0; i < 4; ++i) {
      qk[seg * 8 + i] = qa[i] * ka[i];
      qk[seg * 8 + 4 + i] = qb[i] * kb[i];
      cwv[seg * 8 + i] = ca[i];
      cwv[seg * 8 + 4 + i] = cbx[i];
    }
    cbv[seg * 2] = *(const f32x4*)&convb[c0];
    cbv[seg * 2 + 1] = *(const f32x4*)&convb[c0 + 4];
  }
  __syncthreads();

  const int base = l0 - 12;
  f32x4 x0, x1, x2, x3, nx0, nx1, nx2, nx3;
  u16x8 kk0, kk1, vv0, vv1, nk0, nk1, nv0, nv1;

#define LOADROW(r, X0, X1, X2, X3, K0, K1, V0, V1)                             \
  {                                                                            \
    X0 = (f32x4){0.f,0.f,0.f,0.f}; X1 = X0; X2 = X0; X3 = X0;                  \
    K0 = (u16x8){0,0,0,0,0,0,0,0}; K1 = K0; V0 = K0; V1 = K0;                  \
    if ((r) >= l0 - 9 && (r) >= 0) {                                           \
      size_t mr = (size_t)b * LL + (r);                                        \
      X0 = *(const f32x4*)&hidden[mr * HID + ln * 8];                          \
      X1 = *(const f32x4*)&hidden[mr * HID + ln * 8 + 4];                      \
      X2 = *(const f32x4*)&hidden[mr * HID + 512 + ln * 8];                    \
      X3 = *(const f32x4*)&hidden[mr * HID + 512 + ln * 8 + 4];                \
      K0 = *(const u16x8*)&KV[mr * NKV + ln * 8];                              \
      K1 = *(const u16x8*)&KV[mr * NKV + 512 + ln * 8];                        \
      V0 = *(const u16x8*)&KV[mr * NKV + HID + ln * 8];                        \
      V1 = *(const u16x8*)&KV[mr * NKV + HID + 512 + ln * 8];                  \
    }                                                                          \
  }

  LOADROW(base + w, x0, x1, x2, x3, kk0, kk1, vv0, vv1);

#pragma unroll 1
  for (int g = 0; g < 11; ++g) {
    const int r = base + g * 4 + w;
    if (g < 10) {
      LOADROW(r + 4, nx0, nx1, nx2, nx3, nk0, nk1, nv0, nv1);
    }
    float s0 = 0.f, s1 = 0.f, s2 = 0.f, s3 = 0.f;
#pragma unroll
    for (int e = 0; e < 8; ++e) {
      float xa = (e < 4) ? x0[e] : x1[e - 4];
      float xb = (e < 4) ? x2[e] : x3[e - 4];
      float ka = bf2f(kk0[e]), kb = bf2f(kk1[e]);
      float va = bf2f(vv0[e]), vb = bf2f(vv1[e]);
      s0 += xa * xa + xb * xb;
      s1 += ka * ka + kb * kb;
      s2 += xa * qk[e] * ka + xb * qk[8 + e] * kb;
      s3 += va * va + vb * vb;
    }
#pragma unroll
    for (int mm = 32; mm >= 1; mm >>= 1) {
      s0 += __shfl_xor(s0, mm, 64);
      s1 += __shfl_xor(s1, mm, 64);
      s2 += __shfl_xor(s2, mm, 64);
      s3 += __shfl_xor(s3, mm, 64);
    }
    const float inv = 0.0009765625f;
    float rq = rsqrtf(s0 * inv + EPSF);
    float rk = rsqrtf(s1 * inv + EPSF);
    float gate = 1.f / (1.f + expf(-rq * rk * s2 * 0.03125f));
    float rv = rsqrtf(gate * gate * s3 * inv + EPSF);
    float grv = gate * rv;

    u16x8 h0p, h1p;
#pragma unroll
    for (int e = 0; e < 8; ++e) {
      h0p[e] = f2bf(bf2f(vv0[e]) * grv * cwv[e]);
      h1p[e] = f2bf(bf2f(vv1[e]) * grv * cwv[8 + e]);
    }
    const int slot = r & 15;
    *(u16x8*)&ring[slot][ln * 8] = h0p;
    *(u16x8*)&ring[slot][512 + ln * 8] = h1p;
    __syncthreads();

    if (r >= l0) {
      const int s9 = (r - 9) & 15, s6 = (r - 6) & 15, s3s = (r - 3) & 15;
      size_t mr = (size_t)b * LL + r;
#pragma unroll
      for (int seg = 0; seg < 2; ++seg) {
        u16x8 a9 = *(const u16x8*)&ring[s9][seg * 512 + ln * 8];
        u16x8 a6 = *(const u16x8*)&ring[s6][seg * 512 + ln * 8];
        u16x8 a3 = *(const u16x8*)&ring[s3s][seg * 512 + ln * 8];
        const u16x8 vv = seg ? vv1 : vv0;
        f32x4 ra, rb;
#pragma unroll
        for (int e = 0; e < 8; ++e) {
          const int idx = seg * 8 + e;
          float vf = bf2f(vv[e]);
          float hown = vf * grv * cwv[idx];
          int wi = seg * 512 + ln * 8 + e;
          f32x4 wv = cwt[wi ^ ((wi >> 3) & 7)];
          float y = cbv[seg * 2 + (e >> 2)][e & 3] + bf2f(a9[e]) * wv[0] +
                    bf2f(a6[e]) * wv[1] + bf2f(a3[e]) * wv[2] + hown * wv[3];
          float res = y / (1.f + expf(-y)) + gate * vf;
          if (e < 4) ra[e] = res; else rb[e - 4] = res;
        }
        *(f32x4*)&out[mr * HID + seg * 512 + ln * 8] = ra;
        *(f32x4*)&out[mr * HID + seg * 512 + ln * 8 + 4] = rb;
      }
    }
    __syncthreads();   // reads done before next group's ring writes (16-slot ring)
    x0 = nx0; x1 = nx1; x2 = nx2; x3 = nx3;
    kk0 = nk0; kk1 = nk1; vv0 = nv0; vv1 = nv1;
  }
#undef LOADROW
}

// ---------------- launch ----------------
extern "C" void kernel_launch(void* const* d_in, const int* in_sizes, int n_in,
                              void* d_out, int out_size, void* d_ws, size_t ws_size,
                              hipStream_t stream) {
  const float* hidden   = (const float*)d_in[0];
  const int*   tok      = (const int*)d_in[1];
  const int*   proj     = (const int*)d_in[2];
  const int*   m2       = (const int*)d_in[3];
  const int*   m3       = (const int*)d_in[4];
  const int*   tsz      = (const int*)d_in[5];
  const float* tables   = (const float*)d_in[6];
  const float* wk       = (const float*)d_in[7];
  const float* wv       = (const float*)d_in[8];
  const float* qw       = (const float*)d_in[9];
  const float* kw       = (const float*)d_in[10];
  const float* cnw      = (const float*)d_in[11];
  const float* convw    = (const float*)d_in[12];
  const float* convb    = (const float*)d_in[13];
  float* out = (float*)d_out;

  const int max_s = in_sizes[6] / (2 * 8 * 64);

  char* ws = (char*)d_ws;
  u16* mem = (u16*)ws;                                     // 32 MB  bf16 memory[16384][1024]
  u16* W   = (u16*)(ws + (size_t)33554432);                //  4 MB  bf16 W[2048][1024]
  u16* KV  = (u16*)(ws + (size_t)33554432 + 4194304);      // 64 MB  bf16 kv[16384][2048]

  k_convert_w<<<dim3((NKV * KDIM / 4 + 255) / 256), dim3(256), 0, stream>>>(wk, wv, W);
  k_gather<<<dim3(MTOK / 16), dim3(256), 0, stream>>>(tok, proj, m2, m3, tsz, tables, max_s, mem);
  k_gemm<<<dim3((MTOK / 256) * (NKV / 256)), dim3(512), 0, stream>>>(mem, W, KV);
  k_gateconv<<<dim3(BB * (LL / CR)), dim3(256), 0, stream>>>(hidden, KV, qw, kw, cnw, convw, convb, out);
}

// Round 6
// 146.192 us; speedup vs baseline: 1.1055x; 1.1055x over previous
//
#include <hip/hip_runtime.h>
#include <hip/hip_bf16.h>
#include <math.h>

typedef unsigned short u16;
typedef __bf16 bf16x8 __attribute__((ext_vector_type(8)));
typedef float f32x4 __attribute__((ext_vector_type(4)));
typedef unsigned short u16x4 __attribute__((ext_vector_type(4)));
typedef unsigned short u16x8 __attribute__((ext_vector_type(8)));

#define BB 4
#define LL 4096
#define MTOK (BB*LL)
#define HID 1024
#define NKV 2048
#define KDIM 1024
#define VOCABN 32000
#define EPSF 1e-6f

__device__ __forceinline__ float bf2f(u16 x) {
  unsigned u = ((unsigned)x) << 16;
  return __builtin_bit_cast(float, u);
}
__device__ __forceinline__ u16 f2bf(float f) {
  unsigned u = __builtin_bit_cast(unsigned, f);
  u += 0x7FFFu + ((u >> 16) & 1u);
  return (u16)(u >> 16);
}

// ---------------- kernel 1: fused {hash+gather | w-convert}, block-range split ----------------
// blocks [0, 1024): gather 16 tokens each; blocks [1024, 3072): convert w_k||w_v
__global__ __launch_bounds__(256) void k_gather_conv(
    const int* __restrict__ tok, const int* __restrict__ proj,
    const int* __restrict__ m2, const int* __restrict__ m3,
    const int* __restrict__ tsz, const float* __restrict__ tables,
    int max_s, u16* __restrict__ mem,
    const float* __restrict__ wk, const float* __restrict__ wv,
    u16* __restrict__ W) {
  const int blk = blockIdx.x;
  const int tid = threadIdx.x;
  if (blk >= MTOK / 16) {
    // ---- convert branch ----
    int i = (blk - MTOK / 16) * 256 + tid;
    const int n4 = (NKV * KDIM) / 4;
    const int half = n4 / 2;
    const f32x4* src = (i < half) ? (const f32x4*)wk : (const f32x4*)wv;
    int j = (i < half) ? i : i - half;
    f32x4 v = src[j];
    u16x4 o = { f2bf(v[0]), f2bf(v[1]), f2bf(v[2]), f2bf(v[3]) };
    *(u16x4*)&W[(size_t)i * 4] = o;
    return;
  }
  // ---- gather branch ----
  __shared__ int sidx[16][16];    // [token][table]
  const int m0 = blk * 16;
  const int tt = tid >> 4;        // token 0..15
  const int t = tid & 15;         // table 0..15
  const int m = m0 + tt;
  const int l = m & (LL - 1);

  long long c0, c1 = 0, c2 = 0;
  {
    int tk = tok[m];
    tk = tk < 0 ? 0 : (tk > VOCABN - 1 ? VOCABN - 1 : tk);
    c0 = proj[tk];
  }
  if (l >= 1) {
    int tk = tok[m - 1];
    tk = tk < 0 ? 0 : (tk > VOCABN - 1 ? VOCABN - 1 : tk);
    c1 = proj[tk];
  }
  if (l >= 2) {
    int tk = tok[m - 2];
    tk = tk < 0 ? 0 : (tk > VOCABN - 1 ? VOCABN - 1 : tk);
    c2 = proj[tk];
  }
  int order = t >> 3, h = t & 7;
  long long mix;
  if (order == 0) {
    mix = (c1 * (long long)m2[h * 2 + 0]) ^ (c0 * (long long)m2[h * 2 + 1]);
  } else {
    mix = (c2 * (long long)m3[h * 3 + 0]) ^ (c1 * (long long)m3[h * 3 + 1]) ^
          (c0 * (long long)m3[h * 3 + 2]);
  }
  unsigned long long um = (unsigned long long)(mix < 0 ? -mix : mix);
  unsigned long long usz = (unsigned long long)tsz[t];
  unsigned long long qq = (unsigned long long)((double)um / (double)usz);
  long long r = (long long)(um - qq * usz);
  if (r < 0) r += (long long)usz;
  else if (r >= (long long)usz) r -= (long long)usz;
  sidx[tt][t] = (int)r;
  __syncthreads();

  const int q = t;
#pragma unroll
  for (int it = 0; it < 16; ++it) {
    int idx = sidx[tt][it];
    const f32x4* src = (const f32x4*)(tables + ((size_t)it * (size_t)max_s + (size_t)idx) * 64);
    f32x4 e = src[q];
    u16x4 o = { f2bf(e[0]), f2bf(e[1]), f2bf(e[2]), f2bf(e[3]) };
    *(u16x4*)&mem[(size_t)m * HID + it * 64 + q * 4] = o;
  }
}

// ---------------- kernel 2: 256x256 GEMM, BK=32, 4-buffer 3-deep, counted-lgkm split ----------------
#define GBK2 32
#define BUF2 32768

__device__ __forceinline__ void gload16(const void* g, void* l) {
  __builtin_amdgcn_global_load_lds((__attribute__((address_space(1))) void*)(g),
                                   (__attribute__((address_space(3))) void*)(l), 16, 0, 0);
}
__device__ __forceinline__ int swz32(int x) { return x ^ (((x >> 6) & 3) << 4); }

__global__ __launch_bounds__(512, 2) void k_gemm(const u16* __restrict__ A,
                                                 const u16* __restrict__ Bw,
                                                 u16* __restrict__ C) {
  __shared__ __align__(16) char lds[131072];
  const int d = blockIdx.x;
  const int wg = (d & 7) * 64 + (d >> 3);     // XCD-bijective (512 % 8 == 0)
  const int bm = wg >> 3, bn = wg & 7;
  const int tid = threadIdx.x;
  const int w = tid >> 6, lane = tid & 63;
  const int wm = w >> 2, wn = w & 3;
  const int lm = lane & 15, kg = lane >> 4;

  const int ca0 = w * 2, ca1 = w * 2 + 1;
  const int row0 = ca0 * 16 + (lane >> 2);
  const int row1 = ca1 * 16 + (lane >> 2);
  const int off0 = row0 * KDIM + (((lane & 3) ^ (row0 & 3)) << 3);
  const int off1 = row1 * KDIM + (((lane & 3) ^ (row1 & 3)) << 3);
  const int dstA0 = ca0 * 1024 + lane * 16;
  const int dstA1 = ca1 * 1024 + lane * 16;
  const u16* Ap = A + (size_t)bm * 256 * KDIM;
  const u16* Bp = Bw + (size_t)bn * 256 * KDIM;

  int aro[8], bro[4];
#pragma unroll
  for (int mi = 0; mi < 8; ++mi)
    aro[mi] = swz32((wm * 128 + mi * 16 + lm) * 64 + kg * 16);
#pragma unroll
  for (int ni = 0; ni < 4; ++ni)
    bro[ni] = 16384 + swz32((wn * 64 + ni * 16 + lm) * 64 + kg * 16);

  f32x4 acc[8][4];
#pragma unroll
  for (int i = 0; i < 8; ++i)
#pragma unroll
    for (int j = 0; j < 4; ++j) acc[i][j] = (f32x4){0.f, 0.f, 0.f, 0.f};

#define STGA(kt, bb)                                                       \
  {                                                                        \
    char* bbase = lds + (bb) * BUF2;                                       \
    gload16(Ap + off0 + (kt) * GBK2, bbase + dstA0);                       \
    gload16(Ap + off1 + (kt) * GBK2, bbase + dstA1);                       \
  }
#define STGB(kt, bb)                                                       \
  {                                                                        \
    char* bbase = lds + (bb) * BUF2;                                       \
    gload16(Bp + off0 + (kt) * GBK2, bbase + 16384 + dstA0);               \
    gload16(Bp + off1 + (kt) * GBK2, bbase + 16384 + dstA1);               \
  }

  // One barrier per tile. All 12 ds_reads issued up front; MFMA runs in two
  // halves behind counted lgkmcnt(4)/lgkmcnt(0) so af1's read latency hides
  // under the first MFMA block (no mid-tile barrier).
#define TILE(t, bb, VMS, DOSTG)                                            \
  {                                                                        \
    asm volatile("s_waitcnt vmcnt(" VMS ")" ::: "memory");                 \
    __builtin_amdgcn_s_barrier();                                          \
    const char* buf = lds + (bb) * BUF2;                                   \
    bf16x8 af0[4], bfr[4], af1[4];                                         \
    _Pragma("unroll")                                                      \
    for (int mi = 0; mi < 4; ++mi) af0[mi] = *(const bf16x8*)(buf + aro[mi]); \
    _Pragma("unroll")                                                      \
    for (int ni = 0; ni < 4; ++ni) bfr[ni] = *(const bf16x8*)(buf + bro[ni]); \
    if (DOSTG) STGA((t) + 3, ((bb) + 3) & 3);                              \
    _Pragma("unroll")                                                      \
    for (int mi = 0; mi < 4; ++mi) af1[mi] = *(const bf16x8*)(buf + aro[4 + mi]); \
    if (DOSTG) STGB((t) + 3, ((bb) + 3) & 3);                              \
    __builtin_amdgcn_sched_barrier(0);                                     \
    asm volatile("s_waitcnt lgkmcnt(4)" ::: "memory");                     \
    __builtin_amdgcn_sched_barrier(0);                                     \
    __builtin_amdgcn_s_setprio(1);                                         \
    _Pragma("unroll")                                                      \
    for (int mi = 0; mi < 4; ++mi)                                         \
      _Pragma("unroll")                                                    \
      for (int ni = 0; ni < 4; ++ni)                                       \
        acc[mi][ni] = __builtin_amdgcn_mfma_f32_16x16x32_bf16(af0[mi], bfr[ni], acc[mi][ni], 0, 0, 0); \
    __builtin_amdgcn_s_setprio(0);                                         \
    __builtin_amdgcn_sched_barrier(0);                                     \
    asm volatile("s_waitcnt lgkmcnt(0)" ::: "memory");                     \
    __builtin_amdgcn_sched_barrier(0);                                     \
    __builtin_amdgcn_s_setprio(1);                                         \
    _Pragma("unroll")                                                      \
    for (int mi = 0; mi < 4; ++mi)                                         \
      _Pragma("unroll")                                                    \
      for (int ni = 0; ni < 4; ++ni)                                       \
        acc[4 + mi][ni] = __builtin_amdgcn_mfma_f32_16x16x32_bf16(af1[mi], bfr[ni], acc[4 + mi][ni], 0, 0, 0); \
    __builtin_amdgcn_s_setprio(0);                                         \
  }

  STGA(0, 0); STGB(0, 0);
  STGA(1, 1); STGB(1, 1);
  STGA(2, 2); STGB(2, 2);
#pragma unroll 1
  for (int t4 = 0; t4 < 7; ++t4) {
    const int t = t4 * 4;
    TILE(t + 0, 0, "8", 1);
    TILE(t + 1, 1, "8", 1);
    TILE(t + 2, 2, "8", 1);
    TILE(t + 3, 3, "8", 1);
  }
  TILE(28, 0, "8", 1);   // stages tile 31
  TILE(29, 1, "8", 0);
  TILE(30, 2, "4", 0);
  TILE(31, 3, "0", 0);
#undef STGA
#undef STGB
#undef TILE

  // ---- epilogue: LDS transpose -> coalesced 16B stores ----
  __syncthreads();
  u16* tile = (u16*)lds;
#pragma unroll
  for (int mi = 0; mi < 8; ++mi)
#pragma unroll
    for (int ni = 0; ni < 4; ++ni)
#pragma unroll
      for (int jj = 0; jj < 4; ++jj) {
        int r = wm * 128 + mi * 16 + kg * 4 + jj;
        int ccol = wn * 64 + ni * 16 + lm;
        tile[r * 256 + ccol] = f2bf(acc[mi][ni][jj]);
      }
  __syncthreads();
#pragma unroll
  for (int it = 0; it < 8; ++it) {
    int r = it * 32 + (tid >> 4);
    int cb = (tid & 15) * 32;
    *(f32x4*)((char*)C + ((size_t)(bm * 256 + r) * NKV + bn * 256) * 2 + cb) =
        *(const f32x4*)((char*)tile + r * 512 + cb);
    *(f32x4*)((char*)C + ((size_t)(bm * 256 + r) * NKV + bn * 256) * 2 + cb + 16) =
        *(const f32x4*)((char*)tile + r * 512 + cb + 16);
  }
}

// ---------------- kernel 3: fused gate+conv, wave-per-row, 32-slot ring (round-4 form) ----------------
#define CR 32

__global__ __launch_bounds__(256, 2) void k_gateconv(
    const float* __restrict__ hidden, const u16* __restrict__ KV,
    const float* __restrict__ qw, const float* __restrict__ kw,
    const float* __restrict__ cw, const float* __restrict__ convw,
    const float* __restrict__ convb, float* __restrict__ out) {
  __shared__ u16 ring[32][1024];   // 64KB bf16 h-history, slot = row & 31
  const int blk = blockIdx.x;
  const int b = blk >> 7;
  const int l0 = (blk & 127) * CR;
  const int w = threadIdx.x >> 6, ln = threadIdx.x & 63;

  float qk[16], cwv[16];
  f32x4 wt[16];
  f32x4 cbv[4];
#pragma unroll
  for (int seg = 0; seg < 2; ++seg) {
    int c0 = seg * 512 + ln * 8;
    f32x4 qa = *(const f32x4*)&qw[c0], qb = *(const f32x4*)&qw[c0 + 4];
    f32x4 ka = *(const f32x4*)&kw[c0], kb = *(const f32x4*)&kw[c0 + 4];
    f32x4 ca = *(const f32x4*)&cw[c0], cbx = *(const f32x4*)&cw[c0 + 4];
#pragma unroll
    for (int i = 0; i < 4; ++i) {
      qk[seg * 8 + i] = qa[i] * ka[i];
      qk[seg * 8 + 4 + i] = qb[i] * kb[i];
      cwv[seg * 8 + i] = ca[i];
      cwv[seg * 8 + 4 + i] = cbx[i];
    }
    cbv[seg * 2] = *(const f32x4*)&convb[c0];
    cbv[seg * 2 + 1] = *(const f32x4*)&convb[c0 + 4];
#pragma unroll
    for (int e = 0; e < 8; ++e) wt[seg * 8 + e] = *(const f32x4*)&convw[(c0 + e) * 4];
  }

  const int base = l0 - 12;
  f32x4 x0, x1, x2, x3, nx0, nx1, nx2, nx3;
  u16x8 kk0, kk1, vv0, vv1, nk0, nk1, nv0, nv1;

#define LOADROW(r, X0, X1, X2, X3, K0, K1, V0, V1)                             \
  {                                                                            \
    X0 = (f32x4){0.f,0.f,0.f,0.f}; X1 = X0; X2 = X0; X3 = X0;                  \
    K0 = (u16x8){0,0,0,0,0,0,0,0}; K1 = K0; V0 = K0; V1 = K0;                  \
    if ((r) >= l0 - 9 && (r) >= 0) {                                           \
      size_t mr = (size_t)b * LL + (r);                                        \
      X0 = *(const f32x4*)&hidden[mr * HID + ln * 8];                          \
      X1 = *(const f32x4*)&hidden[mr * HID + ln * 8 + 4];                      \
      X2 = *(const f32x4*)&hidden[mr * HID + 512 + ln * 8];                    \
      X3 = *(const f32x4*)&hidden[mr * HID + 512 + ln * 8 + 4];                \
      K0 = *(const u16x8*)&KV[mr * NKV + ln * 8];                              \
      K1 = *(const u16x8*)&KV[mr * NKV + 512 + ln * 8];                        \
      V0 = *(const u16x8*)&KV[mr * NKV + HID + ln * 8];                        \
      V1 = *(const u16x8*)&KV[mr * NKV + HID + 512 + ln * 8];                  \
    }                                                                          \
  }

  LOADROW(base + w, x0, x1, x2, x3, kk0, kk1, vv0, vv1);

#pragma unroll 1
  for (int g = 0; g < 11; ++g) {
    const int r = base + g * 4 + w;
    if (g < 10) {
      LOADROW(r + 4, nx0, nx1, nx2, nx3, nk0, nk1, nv0, nv1);
    }
    float s0 = 0.f, s1 = 0.f, s2 = 0.f, s3 = 0.f;
#pragma unroll
    for (int e = 0; e < 8; ++e) {
      float xa = (e < 4) ? x0[e] : x1[e - 4];
      float xb = (e < 4) ? x2[e] : x3[e - 4];
      float ka = bf2f(kk0[e]), kb = bf2f(kk1[e]);
      float va = bf2f(vv0[e]), vb = bf2f(vv1[e]);
      s0 += xa * xa + xb * xb;
      s1 += ka * ka + kb * kb;
      s2 += xa * qk[e] * ka + xb * qk[8 + e] * kb;
      s3 += va * va + vb * vb;
    }
#pragma unroll
    for (int mm = 32; mm >= 1; mm >>= 1) {
      s0 += __shfl_xor(s0, mm, 64);
      s1 += __shfl_xor(s1, mm, 64);
      s2 += __shfl_xor(s2, mm, 64);
      s3 += __shfl_xor(s3, mm, 64);
    }
    const float inv = 0.0009765625f;
    float rq = rsqrtf(s0 * inv + EPSF);
    float rk = rsqrtf(s1 * inv + EPSF);
    float gate = 1.f / (1.f + expf(-rq * rk * s2 * 0.03125f));
    float rv = rsqrtf(gate * gate * s3 * inv + EPSF);
    float grv = gate * rv;

    u16x8 h0p, h1p;
#pragma unroll
    for (int e = 0; e < 8; ++e) {
      h0p[e] = f2bf(bf2f(vv0[e]) * grv * cwv[e]);
      h1p[e] = f2bf(bf2f(vv1[e]) * grv * cwv[8 + e]);
    }
    const int slot = r & 31;
    *(u16x8*)&ring[slot][ln * 8] = h0p;
    *(u16x8*)&ring[slot][512 + ln * 8] = h1p;
    __syncthreads();

    if (r >= l0) {
      const int s9 = (r - 9) & 31, s6 = (r - 6) & 31, s3s = (r - 3) & 31;
      size_t mr = (size_t)b * LL + r;
#pragma unroll
      for (int seg = 0; seg < 2; ++seg) {
        u16x8 a9 = *(const u16x8*)&ring[s9][seg * 512 + ln * 8];
        u16x8 a6 = *(const u16x8*)&ring[s6][seg * 512 + ln * 8];
        u16x8 a3 = *(const u16x8*)&ring[s3s][seg * 512 + ln * 8];
        const u16x8 vv = seg ? vv1 : vv0;
        f32x4 ra, rb;
#pragma unroll
        for (int e = 0; e < 8; ++e) {
          const int idx = seg * 8 + e;
          float vf = bf2f(vv[e]);
          float hown = vf * grv * cwv[idx];
          f32x4 wv = wt[idx];
          float y = cbv[seg * 2 + (e >> 2)][e & 3] + bf2f(a9[e]) * wv[0] +
                    bf2f(a6[e]) * wv[1] + bf2f(a3[e]) * wv[2] + hown * wv[3];
          float res = y / (1.f + expf(-y)) + gate * vf;
          if (e < 4) ra[e] = res; else rb[e - 4] = res;
        }
        *(f32x4*)&out[mr * HID + seg * 512 + ln * 8] = ra;
        *(f32x4*)&out[mr * HID + seg * 512 + ln * 8 + 4] = rb;
      }
    }
    x0 = nx0; x1 = nx1; x2 = nx2; x3 = nx3;
    kk0 = nk0; kk1 = nk1; vv0 = nv0; vv1 = nv1;
  }
#undef LOADROW
}

// ---------------- launch ----------------
extern "C" void kernel_launch(void* const* d_in, const int* in_sizes, int n_in,
                              void* d_out, int out_size, void* d_ws, size_t ws_size,
                              hipStream_t stream) {
  const float* hidden   = (const float*)d_in[0];
  const int*   tok      = (const int*)d_in[1];
  const int*   proj     = (const int*)d_in[2];
  const int*   m2       = (const int*)d_in[3];
  const int*   m3       = (const int*)d_in[4];
  const int*   tsz      = (const int*)d_in[5];
  const float* tables   = (const float*)d_in[6];
  const float* wk       = (const float*)d_in[7];
  const float* wv       = (const float*)d_in[8];
  const float* qw       = (const float*)d_in[9];
  const float* kw       = (const float*)d_in[10];
  const float* cnw      = (const float*)d_in[11];
  const float* convw    = (const float*)d_in[12];
  const float* convb    = (const float*)d_in[13];
  float* out = (float*)d_out;

  const int max_s = in_sizes[6] / (2 * 8 * 64);

  char* ws = (char*)d_ws;
  u16* mem = (u16*)ws;                                     // 32 MB  bf16 memory[16384][1024]
  u16* W   = (u16*)(ws + (size_t)33554432);                //  4 MB  bf16 W[2048][1024]
  u16* KV  = (u16*)(ws + (size_t)33554432 + 4194304);      // 64 MB  bf16 kv[16384][2048]

  k_gather_conv<<<dim3(MTOK / 16 + (NKV * KDIM / 4) / 256), dim3(256), 0, stream>>>(
      tok, proj, m2, m3, tsz, tables, max_s, mem, wk, wv, W);
  k_gemm<<<dim3((MTOK / 256) * (NKV / 256)), dim3(512), 0, stream>>>(mem, W, KV);
  k_gateconv<<<dim3(BB * (LL / CR)), dim3(256), 0, stream>>>(hidden, KV, qw, kw, cnw, convw, convb, out);
}